// Round 1
// baseline (345.210 us; speedup 1.0000x reference)
//
#include <hip/hip_runtime.h>
#include <math.h>

typedef __attribute__((ext_vector_type(4))) float f32x4;
typedef __attribute__((ext_vector_type(8))) short s16x8;

#define BM 32
#define BN 256
#define BK 64

__device__ __forceinline__ unsigned short f2bf(float f) {
  unsigned int u = __float_as_uint(f);
  u += 0x7fffu + ((u >> 16) & 1u);
  return (unsigned short)(u >> 16);
}

// ---------------- rowsum -> dinv ----------------
__global__ __launch_bounds__(256) void rowsum_dinv(const float* __restrict__ adj,
                                                   float* __restrict__ dinv, int n) {
  __shared__ float sm[4];
  int row = blockIdx.x;
  const f32x4* p = (const f32x4*)(adj + (size_t)row * n);
  float s = 0.f;
  for (int c = threadIdx.x; c < n / 4; c += 256) {
    f32x4 v = p[c];
    s += v[0] + v[1] + v[2] + v[3];
  }
#pragma unroll
  for (int off = 32; off > 0; off >>= 1) s += __shfl_down(s, off, 64);
  if ((threadIdx.x & 63) == 0) sm[threadIdx.x >> 6] = s;
  __syncthreads();
  if (threadIdx.x == 0) {
    float d = sm[0] + sm[1] + sm[2] + sm[3] + 1.0f;  // deg = rowsum + 1 (identity)
    dinv[row] = 1.0f / sqrtf(d);
  }
}

// ---------------- transpose + convert W -> WT bf16 ----------------
__global__ void convT(const float* __restrict__ W, unsigned short* __restrict__ WT,
                      int K, int N) {
  int i = blockIdx.x * 256 + threadIdx.x;
  if (i < K * N) {
    int k = i / N, nn = i - k * N;
    WT[(size_t)nn * K + k] = f2bf(W[i]);
  }
}

// ---------------- generic GEMM: C[M,N] = A[M,K] * BT[N,K]^T ----------------
// EPI 0: out fp32 = acc * dinv[row]           (big GEMMs; row = node)
// EPI 1: out bf16 = (acc + bias[row])*dinv[col] (transposed small GEMMs)
template <bool AF32, bool BF32, int EPI, bool ADDI>
__global__ __launch_bounds__(256) void gemm_bt(const void* __restrict__ Ap,
                                               const void* __restrict__ BTp,
                                               void* __restrict__ outp,
                                               const float* __restrict__ bias,
                                               const float* __restrict__ dinv,
                                               int M, int N, int K) {
  __shared__ unsigned short lds[2][(BM + BN) * BK];  // 72 KB
  const int tid = threadIdx.x;
  const int m0 = blockIdx.x * BM;
  const int n0 = blockIdx.y * BN;

  const int sr = tid >> 3;        // 0..31
  const int sc = (tid & 7) * 8;   // 0..56 step 8

  const float* Af = (const float*)Ap;
  const unsigned short* Ah = (const unsigned short*)Ap;
  const float* Bf = (const float*)BTp;
  const unsigned short* Bh = (const unsigned short*)BTp;

  f32x4 a_f[2];
  s16x8 a_h;
  f32x4 b_f[8][2];
  s16x8 b_h[8];

  auto stage_load = [&](int k0) {
    if (AF32) {
      const float* p = Af + (size_t)(m0 + sr) * K + k0 + sc;
      a_f[0] = *(const f32x4*)(p);
      a_f[1] = *(const f32x4*)(p + 4);
    } else {
      a_h = *(const s16x8*)(Ah + (size_t)(m0 + sr) * K + k0 + sc);
    }
#pragma unroll
    for (int it = 0; it < 8; ++it) {
      int n = n0 + it * 32 + sr;
      if (BF32) {
        const float* p = Bf + (size_t)n * K + k0 + sc;
        b_f[it][0] = *(const f32x4*)(p);
        b_f[it][1] = *(const f32x4*)(p + 4);
      } else {
        b_h[it] = *(const s16x8*)(Bh + (size_t)n * K + k0 + sc);
      }
    }
  };

  auto stage_write = [&](int buf, int k0) {
    {
      s16x8 v;
      if (AF32) {
#pragma unroll
        for (int j = 0; j < 8; ++j) {
          float x = (j < 4) ? a_f[0][j] : a_f[1][j - 4];
          if (ADDI) {
            if (m0 + sr == k0 + sc + j) x += 1.0f;  // (adj + I)
          }
          v[j] = (short)f2bf(x);
        }
      } else {
        v = a_h;
      }
      int idx = (sr * BK + sc) ^ ((sr & 7) << 3);
      *(s16x8*)(&lds[buf][idx]) = v;
    }
#pragma unroll
    for (int it = 0; it < 8; ++it) {
      int r = it * 32 + sr;
      s16x8 v;
      if (BF32) {
#pragma unroll
        for (int j = 0; j < 8; ++j)
          v[j] = (short)f2bf((j < 4) ? b_f[it][0][j] : b_f[it][1][j - 4]);
      } else {
        v = b_h[it];
      }
      int idx = BM * BK + ((r * BK + sc) ^ ((r & 7) << 3));
      *(s16x8*)(&lds[buf][idx]) = v;
    }
  };

  const int lane = tid & 63;
  const int wv = tid >> 6;        // 0..3, owns 64 output cols
  const int g = lane >> 4, lr = lane & 15;

  int aidx[2][2], bidx[4][2];
#pragma unroll
  for (int m = 0; m < 2; ++m)
#pragma unroll
    for (int ks = 0; ks < 2; ++ks) {
      int r = m * 16 + lr;
      aidx[m][ks] = (r * BK + ks * 32 + g * 8) ^ ((r & 7) << 3);
    }
#pragma unroll
  for (int n = 0; n < 4; ++n)
#pragma unroll
    for (int ks = 0; ks < 2; ++ks) {
      int r = wv * 64 + n * 16 + lr;
      bidx[n][ks] = BM * BK + ((r * BK + ks * 32 + g * 8) ^ ((r & 7) << 3));
    }

  f32x4 acc[2][4];
#pragma unroll
  for (int m = 0; m < 2; ++m)
#pragma unroll
    for (int n = 0; n < 4; ++n) {
      f32x4 z = {0.f, 0.f, 0.f, 0.f};
      acc[m][n] = z;
    }

  auto compute = [&](int buf) {
    s16x8 af[2][2], bfr[4][2];
#pragma unroll
    for (int m = 0; m < 2; ++m)
#pragma unroll
      for (int ks = 0; ks < 2; ++ks)
        af[m][ks] = *(const s16x8*)(&lds[buf][aidx[m][ks]]);
#pragma unroll
    for (int n = 0; n < 4; ++n)
#pragma unroll
      for (int ks = 0; ks < 2; ++ks)
        bfr[n][ks] = *(const s16x8*)(&lds[buf][bidx[n][ks]]);
#pragma unroll
    for (int m = 0; m < 2; ++m)
#pragma unroll
      for (int n = 0; n < 4; ++n)
#pragma unroll
        for (int ks = 0; ks < 2; ++ks)
          acc[m][n] = __builtin_amdgcn_mfma_f32_16x16x32_bf16(af[m][ks], bfr[n][ks],
                                                              acc[m][n], 0, 0, 0);
  };

  stage_load(0);
  stage_write(0, 0);
  __syncthreads();
  int cur = 0;
  const int nt = K / BK;
  for (int t = 0; t < nt; ++t) {
    int k_next = (t + 1) * BK;
    if (t + 1 < nt) stage_load(k_next);   // global loads in flight during MFMA
    compute(cur);
    if (t + 1 < nt) {
      stage_write(cur ^ 1, k_next);       // compiler inserts vmcnt waits
      __syncthreads();                    // one barrier per K-step (dbuf)
      cur ^= 1;
    }
  }

#pragma unroll
  for (int m = 0; m < 2; ++m) {
#pragma unroll
    for (int n = 0; n < 4; ++n) {
      int col = n0 + wv * 64 + n * 16 + lr;
#pragma unroll
      for (int r = 0; r < 4; ++r) {
        int row = m0 + m * 16 + g * 4 + r;
        float v = acc[m][n][r];
        if (EPI == 0) {
          ((float*)outp)[(size_t)row * N + col] = v * dinv[row];
        } else {
          v = (v + bias[row]) * dinv[col];
          ((unsigned short*)outp)[(size_t)row * N + col] = f2bf(v);
        }
      }
    }
  }
}

// ---------------- GELU(exact erf) + LayerNorm over 256, write bf16 ----------------
__global__ __launch_bounds__(256) void gelu_ln(const float* __restrict__ C,
                                               const float* __restrict__ gamma,
                                               const float* __restrict__ beta,
                                               unsigned short* __restrict__ out) {
  __shared__ float sm[4];
  int row = blockIdx.x;
  int c = threadIdx.x;
  float v = C[(size_t)row * 256 + c];
  float gl = 0.5f * v * (1.0f + erff(v * 0.70710678118654752f));
  float s = gl;
#pragma unroll
  for (int off = 32; off > 0; off >>= 1) s += __shfl_down(s, off, 64);
  if ((c & 63) == 0) sm[c >> 6] = s;
  __syncthreads();
  float mu = (sm[0] + sm[1] + sm[2] + sm[3]) * (1.0f / 256.0f);
  __syncthreads();
  float d = gl - mu;
  float s2 = d * d;
#pragma unroll
  for (int off = 32; off > 0; off >>= 1) s2 += __shfl_down(s2, off, 64);
  if ((c & 63) == 0) sm[c >> 6] = s2;
  __syncthreads();
  float var = (sm[0] + sm[1] + sm[2] + sm[3]) * (1.0f / 256.0f);
  float y = d * (1.0f / sqrtf(var + 1e-6f)) * gamma[c] + beta[c];
  out[(size_t)row * 256 + c] = f2bf(y);
}

// ---------------- launch ----------------
extern "C" void kernel_launch(void* const* d_in, const int* in_sizes, int n_in,
                              void* d_out, int out_size, void* d_ws, size_t ws_size,
                              hipStream_t stream) {
  (void)in_sizes; (void)n_in; (void)out_size; (void)ws_size;
  const int N = 8192, IN_DIM = 512, HID = 256;
  const float* x     = (const float*)d_in[0];
  const float* adj   = (const float*)d_in[1];
  const float* W1    = (const float*)d_in[2];
  const float* b1    = (const float*)d_in[3];
  const float* W2    = (const float*)d_in[4];
  const float* b2    = (const float*)d_in[5];
  const float* gamma = (const float*)d_in[6];
  const float* beta  = (const float*)d_in[7];
  float* out = (float*)d_out;

  char* ws = (char*)d_ws;
  float* dinv          = (float*)ws;                                   // 32 KB
  unsigned short* W1T  = (unsigned short*)(ws + (32 << 10));           // 256 KB
  unsigned short* W2T  = (unsigned short*)(ws + (288 << 10));          // 128 KB
  unsigned short* hs1T = (unsigned short*)(ws + (512 << 10));          // 4 MB [256][8192]
  unsigned short* hs2T = (unsigned short*)(ws + (512 << 10) + (4 << 20));   // 4 MB
  unsigned short* hln  = (unsigned short*)(ws + (512 << 10) + (8 << 20));   // 4 MB [8192][256]
  float* C1            = (float*)(ws + (512 << 10) + (12 << 20));      // 8 MB [8192][256]

  // 1) deg -> dinv
  rowsum_dinv<<<N, 256, 0, stream>>>(adj, dinv, N);
  // 2) weights -> transposed bf16
  convT<<<(IN_DIM * HID + 255) / 256, 256, 0, stream>>>(W1, W1T, IN_DIM, HID);
  convT<<<(HID * HID + 255) / 256, 256, 0, stream>>>(W2, W2T, HID, HID);
  // 3) hs1T[h][i] = dinv[i]*(x@W1 + b1)  as GEMM: W1T[256,512] x x[8192,512]^T
  gemm_bt<false, true, 1, false><<<dim3(HID / BM, N / BN), 256, 0, stream>>>(
      W1T, x, hs1T, b1, dinv, HID, N, IN_DIM);
  // 4) C1 = dinv ⊙ ((adj+I) @ hs1)
  gemm_bt<true, false, 0, true><<<dim3(N / BM, HID / BN), 256, 0, stream>>>(
      adj, hs1T, C1, nullptr, dinv, N, HID, N);
  // 5) gelu + layernorm -> hln bf16 [8192,256]
  gelu_ln<<<N, 256, 0, stream>>>(C1, gamma, beta, hln);
  // 6) hs2T[h][i] = dinv[i]*(hln@W2 + b2)
  gemm_bt<false, false, 1, false><<<dim3(HID / BM, N / BN), 256, 0, stream>>>(
      W2T, hln, hs2T, b2, dinv, HID, N, HID);
  // 7) out = dinv ⊙ ((adj+I) @ hs2)
  gemm_bt<true, false, 0, true><<<dim3(N / BM, HID / BN), 256, 0, stream>>>(
      adj, hs2T, out, nullptr, dinv, N, HID, N);
}

// Round 2
// 280.324 us; speedup vs baseline: 1.2315x; 1.2315x over previous
//
#include <hip/hip_runtime.h>
#include <math.h>

typedef __attribute__((ext_vector_type(4))) float f32x4;
typedef __attribute__((ext_vector_type(8))) short s16x8;

#define BM 32
#define BN 256
#define BK 64
#define NBUF 3
#define LDS_TILE ((BM + BN) * BK)  // halfwords per big-gemm buffer

__device__ __forceinline__ unsigned short f2bf(float f) {
  unsigned int u = __float_as_uint(f);
  u += 0x7fffu + ((u >> 16) & 1u);
  return (unsigned short)(u >> 16);
}

__device__ __forceinline__ void gload16(const void* g, void* l) {
  __builtin_amdgcn_global_load_lds(
      (const __attribute__((address_space(1))) void*)g,
      (__attribute__((address_space(3))) void*)l, 16, 0, 0);
}

// ---------------- small GEMM device body: C[M,N] = A^T(KxM) * BT[N,K]^T ----------------
// A is fp32 [K][M] (weight, accessed transposed). EPI 2: fp32 out = acc+bias[row].
// EPI 1: bf16 out = (acc+bias[row])*dinv[col].
template <bool BF32, int EPI>
__device__ __forceinline__ void gemm_small(int bx, unsigned short* ldsb,
                                           const float* __restrict__ A,
                                           const void* __restrict__ BTp,
                                           void* __restrict__ outp,
                                           const float* __restrict__ bias,
                                           const float* __restrict__ dinv,
                                           int M, int N, int K) {
  const int tid = threadIdx.x;
  const int m0 = (bx & (M / BM - 1)) * BM;
  const int n0 = (bx / (M / BM)) * BN;
  const int sr = tid >> 3;
  const int sc = (tid & 7) * 8;
  const float* Bf = (const float*)BTp;
  const unsigned short* Bh = (const unsigned short*)BTp;

  float a_t[8];
  f32x4 b_f[8][2];
  s16x8 b_h[8];

  auto stage_load = [&](int k0) {
#pragma unroll
    for (int j = 0; j < 8; ++j)
      a_t[j] = A[(size_t)(k0 + sc + j) * M + m0 + sr];
#pragma unroll
    for (int it = 0; it < 8; ++it) {
      int n = n0 + it * 32 + sr;
      if (BF32) {
        const float* p = Bf + (size_t)n * K + k0 + sc;
        b_f[it][0] = *(const f32x4*)(p);
        b_f[it][1] = *(const f32x4*)(p + 4);
      } else {
        b_h[it] = *(const s16x8*)(Bh + (size_t)n * K + k0 + sc);
      }
    }
  };

  auto stage_write = [&](int buf) {
    unsigned short* L = ldsb + buf * LDS_TILE;
    {
      s16x8 v;
#pragma unroll
      for (int j = 0; j < 8; ++j) v[j] = (short)f2bf(a_t[j]);
      int idx = (sr * BK + sc) ^ ((sr & 7) << 3);
      *(s16x8*)(L + idx) = v;
    }
#pragma unroll
    for (int it = 0; it < 8; ++it) {
      int r = it * 32 + sr;
      s16x8 w;
      if (BF32) {
#pragma unroll
        for (int j = 0; j < 8; ++j)
          w[j] = (short)f2bf(j < 4 ? b_f[it][0][j] : b_f[it][1][j - 4]);
      } else {
        w = b_h[it];
      }
      int idx = BM * BK + ((r * BK + sc) ^ ((r & 7) << 3));
      *(s16x8*)(L + idx) = w;
    }
  };

  const int lane = tid & 63;
  const int wv = tid >> 6;
  const int g = lane >> 4, lr = lane & 15;

  int aidx[2][2], bidx[4][2];
#pragma unroll
  for (int m = 0; m < 2; ++m)
#pragma unroll
    for (int ks = 0; ks < 2; ++ks) {
      int r = m * 16 + lr;
      aidx[m][ks] = (r * BK + ks * 32 + g * 8) ^ ((r & 7) << 3);
    }
#pragma unroll
  for (int n = 0; n < 4; ++n)
#pragma unroll
    for (int ks = 0; ks < 2; ++ks) {
      int r = wv * 64 + n * 16 + lr;
      bidx[n][ks] = BM * BK + ((r * BK + ks * 32 + g * 8) ^ ((r & 7) << 3));
    }

  f32x4 acc[2][4];
#pragma unroll
  for (int m = 0; m < 2; ++m)
#pragma unroll
    for (int n = 0; n < 4; ++n) {
      f32x4 z = {0.f, 0.f, 0.f, 0.f};
      acc[m][n] = z;
    }

  auto compute = [&](int buf) {
    const unsigned short* L = ldsb + buf * LDS_TILE;
    s16x8 af[2][2], bfr[4][2];
#pragma unroll
    for (int m = 0; m < 2; ++m)
#pragma unroll
      for (int ks = 0; ks < 2; ++ks) af[m][ks] = *(const s16x8*)(L + aidx[m][ks]);
#pragma unroll
    for (int n = 0; n < 4; ++n)
#pragma unroll
      for (int ks = 0; ks < 2; ++ks) bfr[n][ks] = *(const s16x8*)(L + bidx[n][ks]);
#pragma unroll
    for (int m = 0; m < 2; ++m)
#pragma unroll
      for (int n = 0; n < 4; ++n)
#pragma unroll
        for (int ks = 0; ks < 2; ++ks)
          acc[m][n] = __builtin_amdgcn_mfma_f32_16x16x32_bf16(af[m][ks], bfr[n][ks],
                                                              acc[m][n], 0, 0, 0);
  };

  stage_load(0);
  stage_write(0);
  __syncthreads();
  int cur = 0;
  const int nt = K / BK;
  for (int t = 0; t < nt; ++t) {
    if (t + 1 < nt) stage_load((t + 1) * BK);
    compute(cur);
    if (t + 1 < nt) {
      stage_write(cur ^ 1);
      __syncthreads();
      cur ^= 1;
    }
  }

#pragma unroll
  for (int m = 0; m < 2; ++m)
#pragma unroll
    for (int n = 0; n < 4; ++n) {
      int col = n0 + wv * 64 + n * 16 + lr;
#pragma unroll
      for (int r = 0; r < 4; ++r) {
        int row = m0 + m * 16 + g * 4 + r;
        float v = acc[m][n][r];
        if constexpr (EPI == 2) {
          ((float*)outp)[(size_t)row * N + col] = v + bias[row];
        } else {
          ((unsigned short*)outp)[(size_t)row * N + col] = f2bf((v + bias[row]) * dinv[col]);
        }
      }
    }
}

// ---------------- prep: gemm3 blocks [0,256) + adj conv/rowsum blocks [256,2304) ----------------
__global__ __launch_bounds__(256) void prep(const float* __restrict__ adj,
                                            const float* __restrict__ x,
                                            const float* __restrict__ W1,
                                            const float* __restrict__ b1,
                                            unsigned short* __restrict__ adjh,
                                            float* __restrict__ dinv,
                                            float* __restrict__ h1T) {
  __shared__ unsigned short lds[2 * LDS_TILE];
  int bx = blockIdx.x;
  if (bx < 256) {
    // h1T[256][8192] fp32 = (x @ W1 + b1)^T  (no dinv yet)
    gemm_small<true, 2>(bx, lds, W1, x, h1T, b1, nullptr, 256, 8192, 512);
    return;
  }
  bx -= 256;
  float* smf = (float*)lds;
  const int tid = threadIdx.x;
  float psum[4];
#pragma unroll
  for (int rr = 0; rr < 4; ++rr) {
    int row = bx * 4 + rr;
    const float* src = adj + (size_t)row * 8192;
    unsigned short* dst = adjh + (size_t)row * 8192;
    float s = 0.f;
    for (int c = tid * 8; c < 8192; c += 2048) {
      f32x4 v0 = *(const f32x4*)(src + c);
      f32x4 v1 = *(const f32x4*)(src + c + 4);
      s += v0[0] + v0[1] + v0[2] + v0[3] + v1[0] + v1[1] + v1[2] + v1[3];
      if (row >= c && row < c + 8) {  // add identity AFTER summing (deg = rowsum(adj)+1)
        int d = row - c;
        if (d < 4) v0[d] += 1.f; else v1[d - 4] += 1.f;
      }
      s16x8 o;
#pragma unroll
      for (int j = 0; j < 4; ++j) {
        o[j] = (short)f2bf(v0[j]);
        o[j + 4] = (short)f2bf(v1[j]);
      }
      *(s16x8*)(dst + c) = o;
    }
    psum[rr] = s;
  }
#pragma unroll
  for (int rr = 0; rr < 4; ++rr) {
    float s = psum[rr];
#pragma unroll
    for (int off = 32; off > 0; off >>= 1) s += __shfl_down(s, off, 64);
    if ((tid & 63) == 0) smf[(tid >> 6) * 4 + rr] = s;
  }
  __syncthreads();
  if (tid < 4) {
    float tot = smf[tid] + smf[4 + tid] + smf[8 + tid] + smf[12 + tid];
    dinv[bx * 4 + tid] = rsqrtf(tot + 1.0f);
  }
}

// ---------------- hs1T = bf16(h1T * dinv[node]) ----------------
__global__ __launch_bounds__(256) void scale_hs(const float* __restrict__ h1T,
                                                const float* __restrict__ dinv,
                                                unsigned short* __restrict__ hs1T) {
  size_t i = ((size_t)blockIdx.x * 256 + threadIdx.x) * 8;
  f32x4 a = *(const f32x4*)(h1T + i);
  f32x4 b = *(const f32x4*)(h1T + i + 4);
  int k = (int)(i & 8191);
  f32x4 d0 = *(const f32x4*)(dinv + k);
  f32x4 d1 = *(const f32x4*)(dinv + k + 4);
  s16x8 o;
#pragma unroll
  for (int j = 0; j < 4; ++j) {
    o[j] = (short)f2bf(a[j] * d0[j]);
    o[j + 4] = (short)f2bf(b[j] * d1[j]);
  }
  *(s16x8*)(hs1T + i) = o;
}

// ---------------- big GEMM: C[8192,256] = adjh[8192,8192] @ BT[256,8192]^T ----------------
// FUSE_LN: epilogue = dinv[row]*acc -> GELU -> LayerNorm -> bf16 out.
// else:    epilogue = dinv[row]*acc -> fp32 out.
template <bool FUSE_LN>
__global__ __launch_bounds__(256) void gemm_big(const unsigned short* __restrict__ A,
                                                const unsigned short* __restrict__ BT,
                                                void* __restrict__ outp,
                                                const float* __restrict__ dinv,
                                                const float* __restrict__ gamma,
                                                const float* __restrict__ beta) {
  constexpr int K = 8192;
  __shared__ unsigned short lds[NBUF * LDS_TILE];  // 108 KB
  const int tid = threadIdx.x;
  const int m0 = blockIdx.x * BM;
  const int wv = tid >> 6;
  const int lane = tid & 63;
  const int lrow = lane >> 3;           // row within wave's 8-row chunk
  const int swz = ((lane & 7) * 16) ^ (lrow << 4);  // pre-swizzled byte-in-row

  const char* Abase = (const char*)(A + (size_t)(m0 + 8 * wv + lrow) * K) + swz;
  const char* Bbase[8];
#pragma unroll
  for (int it = 0; it < 8; ++it)
    Bbase[it] = (const char*)(BT + (size_t)(it * 32 + 8 * wv + lrow) * K) + swz;

  auto stage = [&](int buf, int k0) {  // 9 global_load_lds per thread
    unsigned short* L = lds + buf * LDS_TILE;
    gload16(Abase + (size_t)k0 * 2, L + wv * 512);
#pragma unroll
    for (int it = 0; it < 8; ++it)
      gload16(Bbase[it] + (size_t)k0 * 2, L + 2048 + it * 2048 + wv * 512);
  };

  const int g = lane >> 4, lr = lane & 15;
  int aidx[2][2], bidx[4][2];
#pragma unroll
  for (int m = 0; m < 2; ++m)
#pragma unroll
    for (int ks = 0; ks < 2; ++ks) {
      int r = m * 16 + lr;
      aidx[m][ks] = r * 64 + ((ks * 32 + g * 8) ^ ((r & 7) << 3));
    }
#pragma unroll
  for (int n = 0; n < 4; ++n)
#pragma unroll
    for (int ks = 0; ks < 2; ++ks) {
      int r = wv * 64 + n * 16 + lr;
      bidx[n][ks] = 2048 + r * 64 + ((ks * 32 + g * 8) ^ ((r & 7) << 3));
    }

  f32x4 acc[2][4];
#pragma unroll
  for (int m = 0; m < 2; ++m)
#pragma unroll
    for (int n = 0; n < 4; ++n) {
      f32x4 z = {0.f, 0.f, 0.f, 0.f};
      acc[m][n] = z;
    }

  stage(0, 0);
  stage(1, BK);
  stage(2, 2 * BK);
  int cur = 0;
  const int nt = K / BK;  // 128
  for (int t = 0; t < nt; ++t) {
    // counted vmcnt: tile t's 9 loads done; t+1/t+2 stay in flight (T4)
    if (t + 2 < nt)      asm volatile("s_waitcnt vmcnt(18)" ::: "memory");
    else if (t + 1 < nt) asm volatile("s_waitcnt vmcnt(9)" ::: "memory");
    else                 asm volatile("s_waitcnt vmcnt(0)" ::: "memory");
    __builtin_amdgcn_sched_barrier(0);
    asm volatile("s_barrier" ::: "memory");
    __builtin_amdgcn_sched_barrier(0);

    const unsigned short* L = lds + cur * LDS_TILE;
    s16x8 af[2][2], bfr[4][2];
#pragma unroll
    for (int m = 0; m < 2; ++m)
#pragma unroll
      for (int ks = 0; ks < 2; ++ks) af[m][ks] = *(const s16x8*)(L + aidx[m][ks]);
#pragma unroll
    for (int n = 0; n < 4; ++n)
#pragma unroll
      for (int ks = 0; ks < 2; ++ks) bfr[n][ks] = *(const s16x8*)(L + bidx[n][ks]);
#pragma unroll
    for (int m = 0; m < 2; ++m)
#pragma unroll
      for (int n = 0; n < 4; ++n)
#pragma unroll
        for (int ks = 0; ks < 2; ++ks)
          acc[m][n] = __builtin_amdgcn_mfma_f32_16x16x32_bf16(af[m][ks], bfr[n][ks],
                                                              acc[m][n], 0, 0, 0);

    __builtin_amdgcn_sched_barrier(0);
    asm volatile("s_barrier" ::: "memory");  // all waves done reading buf[cur]
    __builtin_amdgcn_sched_barrier(0);
    if (t + 3 < nt) stage(cur, (t + 3) * BK);
    cur = (cur == NBUF - 1) ? 0 : cur + 1;
  }

  float di[2][4];
#pragma unroll
  for (int m = 0; m < 2; ++m)
#pragma unroll
    for (int r = 0; r < 4; ++r) di[m][r] = dinv[m0 + m * 16 + g * 4 + r];

  if constexpr (!FUSE_LN) {
    float* fout = (float*)outp;
#pragma unroll
    for (int m = 0; m < 2; ++m)
#pragma unroll
      for (int n = 0; n < 4; ++n) {
        int col = wv * 64 + n * 16 + lr;
#pragma unroll
        for (int r = 0; r < 4; ++r) {
          int row = m0 + m * 16 + g * 4 + r;
          fout[(size_t)row * 256 + col] = acc[m][n][r] * di[m][r];
        }
      }
  } else {
    // GELU (exact erf) then LayerNorm over the 256 cols this block fully owns
    float gv[2][4][4];
#pragma unroll
    for (int m = 0; m < 2; ++m)
#pragma unroll
      for (int n = 0; n < 4; ++n)
#pragma unroll
        for (int r = 0; r < 4; ++r) {
          float v = acc[m][n][r] * di[m][r];
          gv[m][n][r] = 0.5f * v * (1.0f + erff(v * 0.70710678118654752440f));
        }
    float* smf = (float*)lds;  // [0,128): row sums; [128,256): row sumsq
#pragma unroll
    for (int m = 0; m < 2; ++m)
#pragma unroll
      for (int r = 0; r < 4; ++r) {
        float s = 0.f, q = 0.f;
#pragma unroll
        for (int n = 0; n < 4; ++n) {
          float xv = gv[m][n][r];
          s += xv;
          q += xv * xv;
        }
#pragma unroll
        for (int off = 1; off < 16; off <<= 1) {
          s += __shfl_xor(s, off, 64);
          q += __shfl_xor(q, off, 64);
        }
        if (lr == 0) {
          int row = m * 16 + g * 4 + r;
          smf[row * 4 + wv] = s;
          smf[128 + row * 4 + wv] = q;
        }
      }
    __syncthreads();
    unsigned short* hout = (unsigned short*)outp;
    float gam[4], bet[4];
#pragma unroll
    for (int n = 0; n < 4; ++n) {
      int col = wv * 64 + n * 16 + lr;
      gam[n] = gamma[col];
      bet[n] = beta[col];
    }
#pragma unroll
    for (int m = 0; m < 2; ++m)
#pragma unroll
      for (int r = 0; r < 4; ++r) {
        int row = m * 16 + g * 4 + r;
        f32x4 sv = *(const f32x4*)(smf + row * 4);
        f32x4 qv = *(const f32x4*)(smf + 128 + row * 4);
        float mu = (sv[0] + sv[1] + sv[2] + sv[3]) * (1.0f / 256.0f);
        float ex2 = (qv[0] + qv[1] + qv[2] + qv[3]) * (1.0f / 256.0f);
        float rs = rsqrtf(fmaxf(ex2 - mu * mu, 0.f) + 1e-6f);
#pragma unroll
        for (int n = 0; n < 4; ++n) {
          int col = wv * 64 + n * 16 + lr;
          float y = (gv[m][n][r] - mu) * rs * gam[n] + bet[n];
          hout[(size_t)(m0 + row) * 256 + col] = f2bf(y);
        }
      }
  }
}

// ---------------- GEMM6 wrapper: hs2T = bf16((hln @ W2 + b2)^T * dinv[col]) ----------------
__global__ __launch_bounds__(256) void gemm6_k(const float* __restrict__ W2,
                                               const unsigned short* __restrict__ hln,
                                               unsigned short* __restrict__ hs2T,
                                               const float* __restrict__ b2,
                                               const float* __restrict__ dinv) {
  __shared__ unsigned short lds[2 * LDS_TILE];
  gemm_small<false, 1>(blockIdx.x, lds, W2, hln, hs2T, b2, dinv, 256, 8192, 256);
}

// ---------------- launch ----------------
extern "C" void kernel_launch(void* const* d_in, const int* in_sizes, int n_in,
                              void* d_out, int out_size, void* d_ws, size_t ws_size,
                              hipStream_t stream) {
  (void)in_sizes; (void)n_in; (void)out_size; (void)ws_size;
  const float* x     = (const float*)d_in[0];
  const float* adj   = (const float*)d_in[1];
  const float* W1    = (const float*)d_in[2];
  const float* b1    = (const float*)d_in[3];
  const float* W2    = (const float*)d_in[4];
  const float* b2    = (const float*)d_in[5];
  const float* gamma = (const float*)d_in[6];
  const float* beta  = (const float*)d_in[7];
  float* out = (float*)d_out;

  char* ws = (char*)d_ws;
  float* dinv          = (float*)ws;                                  // 32 KB
  float* h1T           = (float*)(ws + (1 << 20));                    // 8 MB  [256][8192] fp32
  unsigned short* hs1T = (unsigned short*)(ws + (16 << 20));          // 4 MB  [256][8192] bf16
  unsigned short* hln  = (unsigned short*)(ws + (24 << 20));          // 4 MB  [8192][256] bf16
  unsigned short* hs2T = (unsigned short*)(ws + (32 << 20));          // 4 MB  [256][8192] bf16
  unsigned short* adjh = (unsigned short*)(ws + (64 << 20));          // 128 MB [8192][8192] bf16 (adj+I)

  // 1) gemm3 (h1T, no dinv) + adj->bf16(+I) + rowsum->dinv, fused
  prep<<<2304, 256, 0, stream>>>(adj, x, W1, b1, adjh, dinv, h1T);
  // 2) hs1T = bf16(h1T * dinv[node])
  scale_hs<<<1024, 256, 0, stream>>>(h1T, dinv, hs1T);
  // 3) hln = LN(GELU(dinv ⊙ (adj+I) @ hs1))   (fused epilogue)
  gemm_big<true><<<256, 256, 0, stream>>>(adjh, hs1T, hln, dinv, gamma, beta);
  // 4) hs2T = bf16((hln @ W2 + b2)^T ⊙ dinv[node])
  gemm6_k<<<256, 256, 0, stream>>>(W2, hln, hs2T, b2, dinv);
  // 5) out = dinv ⊙ (adj+I) @ hs2
  gemm_big<false><<<256, 256, 0, stream>>>(adjh, hs2T, out, dinv, nullptr, nullptr);
}

// Round 3
// 228.170 us; speedup vs baseline: 1.5130x; 1.2286x over previous
//
#include <hip/hip_runtime.h>
#include <math.h>

typedef __attribute__((ext_vector_type(4))) float f32x4;
typedef __attribute__((ext_vector_type(8))) short s16x8;

// small-GEMM tile
#define BM 32
#define BN 256
#define BK 64
#define LDS_TILE ((BM + BN) * BK)

// big-GEMM tile
#define BM2 64
#define BN2 256
#define BK2 64
#define NBUF 3
#define LDS_TILE2 ((BM2 + BN2) * BK2)  // 20480 halfwords = 40 KB
#define KFULL 8192
#define KH 4096  // split-K half

__device__ __forceinline__ unsigned short f2bf(float f) {
  unsigned int u = __float_as_uint(f);
  u += 0x7fffu + ((u >> 16) & 1u);
  return (unsigned short)(u >> 16);
}
__device__ __forceinline__ float bf2f(unsigned short h) {
  unsigned int u = ((unsigned int)h) << 16;
  return __uint_as_float(u);
}

__device__ __forceinline__ void gload16(const void* g, void* l) {
  __builtin_amdgcn_global_load_lds(
      (const __attribute__((address_space(1))) void*)g,
      (__attribute__((address_space(3))) void*)l, 16, 0, 0);
}

// ---------------- small GEMM device body: C[M,N] = A^T(KxM) * BT[N,K]^T ----------------
// EPI 3: bf16 out = acc + bias[row]           (gemm3: h1, no dinv yet)
// EPI 1: bf16 out = (acc + bias[row])*dinv[col] (gemm6)
template <bool BF32, int EPI>
__device__ __forceinline__ void gemm_small(int bx, unsigned short* ldsb,
                                           const float* __restrict__ A,
                                           const void* __restrict__ BTp,
                                           void* __restrict__ outp,
                                           const float* __restrict__ bias,
                                           const float* __restrict__ dinv,
                                           int M, int N, int K) {
  const int tid = threadIdx.x;
  const int m0 = (bx & (M / BM - 1)) * BM;
  const int n0 = (bx / (M / BM)) * BN;
  const int sr = tid >> 3;
  const int sc = (tid & 7) * 8;
  const float* Bf = (const float*)BTp;
  const unsigned short* Bh = (const unsigned short*)BTp;

  float a_t[8];
  f32x4 b_f[8][2];
  s16x8 b_h[8];

  auto stage_load = [&](int k0) {
#pragma unroll
    for (int j = 0; j < 8; ++j)
      a_t[j] = A[(size_t)(k0 + sc + j) * M + m0 + sr];
#pragma unroll
    for (int it = 0; it < 8; ++it) {
      int n = n0 + it * 32 + sr;
      if (BF32) {
        const float* p = Bf + (size_t)n * K + k0 + sc;
        b_f[it][0] = *(const f32x4*)(p);
        b_f[it][1] = *(const f32x4*)(p + 4);
      } else {
        b_h[it] = *(const s16x8*)(Bh + (size_t)n * K + k0 + sc);
      }
    }
  };

  auto stage_write = [&](int buf) {
    unsigned short* L = ldsb + buf * LDS_TILE;
    {
      s16x8 v;
#pragma unroll
      for (int j = 0; j < 8; ++j) v[j] = (short)f2bf(a_t[j]);
      int idx = (sr * BK + sc) ^ ((sr & 7) << 3);
      *(s16x8*)(L + idx) = v;
    }
#pragma unroll
    for (int it = 0; it < 8; ++it) {
      int r = it * 32 + sr;
      s16x8 w;
      if (BF32) {
#pragma unroll
        for (int j = 0; j < 8; ++j)
          w[j] = (short)f2bf(j < 4 ? b_f[it][0][j] : b_f[it][1][j - 4]);
      } else {
        w = b_h[it];
      }
      int idx = BM * BK + ((r * BK + sc) ^ ((r & 7) << 3));
      *(s16x8*)(L + idx) = w;
    }
  };

  const int lane = tid & 63;
  const int wv = tid >> 6;
  const int g = lane >> 4, lr = lane & 15;

  int aidx[2][2], bidx[4][2];
#pragma unroll
  for (int m = 0; m < 2; ++m)
#pragma unroll
    for (int ks = 0; ks < 2; ++ks) {
      int r = m * 16 + lr;
      aidx[m][ks] = (r * BK + ks * 32 + g * 8) ^ ((r & 7) << 3);
    }
#pragma unroll
  for (int n = 0; n < 4; ++n)
#pragma unroll
    for (int ks = 0; ks < 2; ++ks) {
      int r = wv * 64 + n * 16 + lr;
      bidx[n][ks] = BM * BK + ((r * BK + ks * 32 + g * 8) ^ ((r & 7) << 3));
    }

  f32x4 acc[2][4];
#pragma unroll
  for (int m = 0; m < 2; ++m)
#pragma unroll
    for (int n = 0; n < 4; ++n) {
      f32x4 z = {0.f, 0.f, 0.f, 0.f};
      acc[m][n] = z;
    }

  auto compute = [&](int buf) {
    const unsigned short* L = ldsb + buf * LDS_TILE;
    s16x8 af[2][2], bfr[4][2];
#pragma unroll
    for (int m = 0; m < 2; ++m)
#pragma unroll
      for (int ks = 0; ks < 2; ++ks) af[m][ks] = *(const s16x8*)(L + aidx[m][ks]);
#pragma unroll
    for (int n = 0; n < 4; ++n)
#pragma unroll
      for (int ks = 0; ks < 2; ++ks) bfr[n][ks] = *(const s16x8*)(L + bidx[n][ks]);
#pragma unroll
    for (int m = 0; m < 2; ++m)
#pragma unroll
      for (int n = 0; n < 4; ++n)
#pragma unroll
        for (int ks = 0; ks < 2; ++ks)
          acc[m][n] = __builtin_amdgcn_mfma_f32_16x16x32_bf16(af[m][ks], bfr[n][ks],
                                                              acc[m][n], 0, 0, 0);
  };

  stage_load(0);
  stage_write(0);
  __syncthreads();
  int cur = 0;
  const int nt = K / BK;
  for (int t = 0; t < nt; ++t) {
    if (t + 1 < nt) stage_load((t + 1) * BK);
    compute(cur);
    if (t + 1 < nt) {
      stage_write(cur ^ 1);
      __syncthreads();
      cur ^= 1;
    }
  }

#pragma unroll
  for (int m = 0; m < 2; ++m)
#pragma unroll
    for (int n = 0; n < 4; ++n) {
      int col = n0 + wv * 64 + n * 16 + lr;
#pragma unroll
      for (int r = 0; r < 4; ++r) {
        int row = m0 + m * 16 + g * 4 + r;
        float v = acc[m][n][r];
        if constexpr (EPI == 3) {
          ((unsigned short*)outp)[(size_t)row * N + col] = f2bf(v + bias[row]);
        } else {
          ((unsigned short*)outp)[(size_t)row * N + col] = f2bf((v + bias[row]) * dinv[col]);
        }
      }
    }
}

// ---------------- prep: gemm3 blocks [0,256) + adj conv/rowsum blocks [256,4352) ----------------
__global__ __launch_bounds__(256) void prep(const float* __restrict__ adj,
                                            const float* __restrict__ x,
                                            const float* __restrict__ W1,
                                            const float* __restrict__ b1,
                                            unsigned short* __restrict__ adjh,
                                            float* __restrict__ dinv,
                                            unsigned short* __restrict__ h1) {
  __shared__ unsigned short lds[2 * LDS_TILE];
  int bx = blockIdx.x;
  if (bx < 256) {
    // h1[256][8192] bf16 = (x @ W1 + b1)^T  (no dinv yet)
    gemm_small<true, 3>(bx, lds, W1, x, h1, b1, nullptr, 256, 8192, 512);
    return;
  }
  bx -= 256;
  float* smf = (float*)lds;
  const int tid = threadIdx.x;
  float psum[2];
#pragma unroll
  for (int rr = 0; rr < 2; ++rr) {
    int row = bx * 2 + rr;
    const float* src = adj + (size_t)row * 8192;
    unsigned short* dst = adjh + (size_t)row * 8192;
    float s = 0.f;
    for (int c = tid * 8; c < 8192; c += 2048) {
      f32x4 v0 = *(const f32x4*)(src + c);
      f32x4 v1 = *(const f32x4*)(src + c + 4);
      s += v0[0] + v0[1] + v0[2] + v0[3] + v1[0] + v1[1] + v1[2] + v1[3];
      if (row >= c && row < c + 8) {  // add identity AFTER summing (deg = rowsum(adj)+1)
        int d = row - c;
        if (d < 4) v0[d] += 1.f; else v1[d - 4] += 1.f;
      }
      s16x8 o;
#pragma unroll
      for (int j = 0; j < 4; ++j) {
        o[j] = (short)f2bf(v0[j]);
        o[j + 4] = (short)f2bf(v1[j]);
      }
      *(s16x8*)(dst + c) = o;
    }
    psum[rr] = s;
  }
#pragma unroll
  for (int rr = 0; rr < 2; ++rr) {
    float s = psum[rr];
#pragma unroll
    for (int off = 32; off > 0; off >>= 1) s += __shfl_down(s, off, 64);
    if ((tid & 63) == 0) smf[rr * 4 + (tid >> 6)] = s;
  }
  __syncthreads();
  if (tid < 2) {
    float tot = smf[tid * 4] + smf[tid * 4 + 1] + smf[tid * 4 + 2] + smf[tid * 4 + 3];
    dinv[bx * 2 + tid] = rsqrtf(tot + 1.0f);
  }
}

// ---------------- hs1T = bf16(h1 * dinv[node]) ----------------
__global__ __launch_bounds__(256) void scale_hs(const unsigned short* __restrict__ h1,
                                                const float* __restrict__ dinv,
                                                unsigned short* __restrict__ hs1T) {
  size_t i = ((size_t)blockIdx.x * 256 + threadIdx.x) * 8;
  s16x8 v = *(const s16x8*)(h1 + i);
  int k = (int)(i & 8191);
  f32x4 d0 = *(const f32x4*)(dinv + k);
  f32x4 d1 = *(const f32x4*)(dinv + k + 4);
  s16x8 o;
#pragma unroll
  for (int j = 0; j < 4; ++j) {
    o[j] = (short)f2bf(bf2f((unsigned short)v[j]) * d0[j]);
    o[j + 4] = (short)f2bf(bf2f((unsigned short)v[j + 4]) * d1[j]);
  }
  *(s16x8*)(hs1T + i) = o;
}

// ---------------- big GEMM (split-K=2): P[z][8192][256] += adjh[.] @ BT[.]^T ----------------
// 256 blocks: blockIdx.x = z*128 + m-tile. 512 threads, 8 waves (2 M-halves x 4 N-quarters).
__global__ __launch_bounds__(512) void gemm_big(const unsigned short* __restrict__ A,
                                                const unsigned short* __restrict__ BT,
                                                float* __restrict__ P) {
  __shared__ unsigned short lds[NBUF * LDS_TILE2];  // 120 KB
  const int tid = threadIdx.x;
  const int mt = blockIdx.x & 127;
  const int z = blockIdx.x >> 7;
  const int m0 = mt * BM2;

  const int w = tid >> 6, l = tid & 63;
  const int lr8 = l >> 3;
  const int swz = ((l & 7) * 16) ^ (lr8 << 4);  // pre-swizzled byte-in-row (matches read XOR)

  const char* Asrc = (const char*)(A + (size_t)(m0 + w * 8 + lr8) * KFULL + (size_t)z * KH) + swz;
  const char* Bsrc[4];
#pragma unroll
  for (int it = 0; it < 4; ++it)
    Bsrc[it] = (const char*)(BT + (size_t)(it * 64 + w * 8 + lr8) * KFULL + (size_t)z * KH) + swz;

  auto stage = [&](int buf, int k0) {  // 5 global_load_lds per thread
    unsigned short* L = lds + buf * LDS_TILE2;
    gload16(Asrc + (size_t)k0 * 2, L + w * 512);
#pragma unroll
    for (int it = 0; it < 4; ++it)
      gload16(Bsrc[it] + (size_t)k0 * 2, L + 4096 + it * 4096 + w * 512);
  };

  const int wr = w >> 2, wc = w & 3;
  const int g = l >> 4, lr = l & 15;
  int aidx[2][2], bidx[4][2];
#pragma unroll
  for (int m = 0; m < 2; ++m)
#pragma unroll
    for (int ks = 0; ks < 2; ++ks) {
      int r = wr * 32 + m * 16 + lr;
      aidx[m][ks] = r * 64 + ((ks * 32 + g * 8) ^ ((r & 7) << 3));
    }
#pragma unroll
  for (int n = 0; n < 4; ++n)
#pragma unroll
    for (int ks = 0; ks < 2; ++ks) {
      int r = wc * 64 + n * 16 + lr;
      bidx[n][ks] = 4096 + r * 64 + ((ks * 32 + g * 8) ^ ((r & 7) << 3));
    }

  f32x4 acc[2][4];
#pragma unroll
  for (int m = 0; m < 2; ++m)
#pragma unroll
    for (int n = 0; n < 4; ++n) {
      f32x4 zz = {0.f, 0.f, 0.f, 0.f};
      acc[m][n] = zz;
    }

  stage(0, 0);
  stage(1, BK2);
  stage(2, 2 * BK2);
  int cur = 0;
  const int nt = KH / BK2;  // 64
  for (int t = 0; t < nt; ++t) {
    if (t + 2 < nt)      asm volatile("s_waitcnt vmcnt(10)" ::: "memory");
    else if (t + 1 < nt) asm volatile("s_waitcnt vmcnt(5)" ::: "memory");
    else                 asm volatile("s_waitcnt vmcnt(0)" ::: "memory");
    __builtin_amdgcn_sched_barrier(0);
    asm volatile("s_barrier" ::: "memory");
    __builtin_amdgcn_sched_barrier(0);

    const unsigned short* L = lds + cur * LDS_TILE2;
    s16x8 af[2][2], bfr[4][2];
#pragma unroll
    for (int m = 0; m < 2; ++m)
#pragma unroll
      for (int ks = 0; ks < 2; ++ks) af[m][ks] = *(const s16x8*)(L + aidx[m][ks]);
#pragma unroll
    for (int n = 0; n < 4; ++n)
#pragma unroll
      for (int ks = 0; ks < 2; ++ks) bfr[n][ks] = *(const s16x8*)(L + bidx[n][ks]);
#pragma unroll
    for (int m = 0; m < 2; ++m)
#pragma unroll
      for (int n = 0; n < 4; ++n)
#pragma unroll
        for (int ks = 0; ks < 2; ++ks)
          acc[m][n] = __builtin_amdgcn_mfma_f32_16x16x32_bf16(af[m][ks], bfr[n][ks],
                                                              acc[m][n], 0, 0, 0);

    __builtin_amdgcn_sched_barrier(0);
    asm volatile("s_barrier" ::: "memory");  // all waves done reading buf[cur]
    __builtin_amdgcn_sched_barrier(0);
    if (t + 3 < nt) stage(cur, (t + 3) * BK2);
    cur = (cur == NBUF - 1) ? 0 : cur + 1;
  }

  float* Pz = P + (size_t)z * 8192 * 256;
#pragma unroll
  for (int m = 0; m < 2; ++m)
#pragma unroll
    for (int n = 0; n < 4; ++n) {
      int col = wc * 64 + n * 16 + lr;
#pragma unroll
      for (int r = 0; r < 4; ++r) {
        int row = m0 + wr * 32 + m * 16 + g * 4 + r;
        Pz[(size_t)row * 256 + col] = acc[m][n][r];
      }
    }
}

// ---------------- reduce1: hln = LN(GELU((P0+P1)*dinv[row])), bf16 out ----------------
__global__ __launch_bounds__(256) void reduce_ln(const float* __restrict__ P,
                                                 const float* __restrict__ dinv,
                                                 const float* __restrict__ gamma,
                                                 const float* __restrict__ beta,
                                                 unsigned short* __restrict__ hln) {
  int row = blockIdx.x * 4 + (threadIdx.x >> 6);
  int l = threadIdx.x & 63;
  const float* p0 = P + (size_t)row * 256 + l * 4;
  const float* p1 = p0 + (size_t)8192 * 256;
  f32x4 a = *(const f32x4*)p0;
  f32x4 b = *(const f32x4*)p1;
  float di = dinv[row];
  float gl[4];
  float s = 0.f, q = 0.f;
#pragma unroll
  for (int j = 0; j < 4; ++j) {
    float v = (a[j] + b[j]) * di;
    float gv = 0.5f * v * (1.0f + erff(v * 0.70710678118654752440f));
    gl[j] = gv;
    s += gv;
    q += gv * gv;
  }
#pragma unroll
  for (int off = 1; off < 64; off <<= 1) {
    s += __shfl_xor(s, off, 64);
    q += __shfl_xor(q, off, 64);
  }
  float mu = s * (1.0f / 256.0f);
  float var = q * (1.0f / 256.0f) - mu * mu;
  float rs = rsqrtf(fmaxf(var, 0.f) + 1e-6f);
  f32x4 gm = *(const f32x4*)(gamma + l * 4);
  f32x4 bt = *(const f32x4*)(beta + l * 4);
  unsigned short o4[4];
#pragma unroll
  for (int j = 0; j < 4; ++j)
    o4[j] = f2bf((gl[j] - mu) * rs * gm[j] + bt[j]);
  *(unsigned long long*)(hln + (size_t)row * 256 + l * 4) =
      *(const unsigned long long*)o4;
}

// ---------------- reduce2: out fp32 = (P0+P1)*dinv[row] ----------------
__global__ __launch_bounds__(256) void reduce_sc(const float* __restrict__ P,
                                                 const float* __restrict__ dinv,
                                                 float* __restrict__ out) {
  size_t i = ((size_t)blockIdx.x * 256 + threadIdx.x) * 4;
  int row = (int)(i >> 8);
  f32x4 a = *(const f32x4*)(P + i);
  f32x4 b = *(const f32x4*)(P + (size_t)8192 * 256 + i);
  float di = dinv[row];
  f32x4 o;
#pragma unroll
  for (int j = 0; j < 4; ++j) o[j] = (a[j] + b[j]) * di;
  *(f32x4*)(out + i) = o;
}

// ---------------- GEMM6: hs2T = bf16((hln @ W2 + b2)^T * dinv[col]) ----------------
__global__ __launch_bounds__(256) void gemm6_k(const float* __restrict__ W2,
                                               const unsigned short* __restrict__ hln,
                                               unsigned short* __restrict__ hs2T,
                                               const float* __restrict__ b2,
                                               const float* __restrict__ dinv) {
  __shared__ unsigned short lds[2 * LDS_TILE];
  gemm_small<false, 1>(blockIdx.x, lds, W2, hln, hs2T, b2, dinv, 256, 8192, 256);
}

// ---------------- launch ----------------
extern "C" void kernel_launch(void* const* d_in, const int* in_sizes, int n_in,
                              void* d_out, int out_size, void* d_ws, size_t ws_size,
                              hipStream_t stream) {
  (void)in_sizes; (void)n_in; (void)out_size; (void)ws_size;
  const float* x     = (const float*)d_in[0];
  const float* adj   = (const float*)d_in[1];
  const float* W1    = (const float*)d_in[2];
  const float* b1    = (const float*)d_in[3];
  const float* W2    = (const float*)d_in[4];
  const float* b2    = (const float*)d_in[5];
  const float* gamma = (const float*)d_in[6];
  const float* beta  = (const float*)d_in[7];
  float* out = (float*)d_out;

  char* ws = (char*)d_ws;
  float* dinv          = (float*)ws;                          // 32 KB
  unsigned short* h1   = (unsigned short*)(ws + (1 << 20));   // 4 MB [256][8192] bf16 (pre-dinv)
  unsigned short* hs1T = (unsigned short*)(ws + (8 << 20));   // 4 MB [256][8192]
  unsigned short* hln  = (unsigned short*)(ws + (16 << 20));  // 4 MB [8192][256]
  unsigned short* hs2T = (unsigned short*)(ws + (24 << 20));  // 4 MB [256][8192]
  float* P             = (float*)(ws + (32 << 20));           // 16 MB [2][8192][256] fp32
  unsigned short* adjh = (unsigned short*)(ws + (64 << 20));  // 128 MB [8192][8192] bf16 (adj+I)

  // 1) gemm3 (h1 bf16, no dinv) + adj->bf16(+I) + rowsum->dinv, fused
  prep<<<4352, 256, 0, stream>>>(adj, x, W1, b1, adjh, dinv, h1);
  // 2) hs1T = bf16(h1 * dinv[node])
  scale_hs<<<1024, 256, 0, stream>>>(h1, dinv, hs1T);
  // 3) P = split-K partials of (adj+I) @ hs1
  gemm_big<<<256, 512, 0, stream>>>(adjh, hs1T, P);
  // 4) hln = LN(GELU((P0+P1)*dinv[row]))
  reduce_ln<<<2048, 256, 0, stream>>>(P, dinv, gamma, beta, hln);
  // 5) hs2T = bf16((hln @ W2 + b2)^T * dinv[node])
  gemm6_k<<<256, 256, 0, stream>>>(W2, hln, hs2T, b2, dinv);
  // 6) P = split-K partials of (adj+I) @ hs2
  gemm_big<<<256, 512, 0, stream>>>(adjh, hs2T, P);
  // 7) out = (P0+P1)*dinv[row]
  reduce_sc<<<2048, 256, 0, stream>>>(P, dinv, out);
}

// Round 4
// 205.887 us; speedup vs baseline: 1.6767x; 1.1082x over previous
//
#include <hip/hip_runtime.h>
#include <math.h>

typedef __attribute__((ext_vector_type(4))) float f32x4;
typedef __attribute__((ext_vector_type(8))) short s16x8;

// small-GEMM tile
#define BM 32
#define BN 256
#define BK 64
#define LDS_TILE ((BM + BN) * BK)

// big-GEMM tile
#define BM2 128
#define BN2 256
#define BK2 64
#define NBUF 3
#define LDS_TILE2 ((BM2 + BN2) * BK2)  // 24576 halfwords = 48 KB
#define KFULL 8192
#define ZSPLIT 4
#define KQ (KFULL / ZSPLIT)  // 2048

__device__ __forceinline__ unsigned short f2bf(float f) {
  unsigned int u = __float_as_uint(f);
  u += 0x7fffu + ((u >> 16) & 1u);
  return (unsigned short)(u >> 16);
}
__device__ __forceinline__ float bf2f(unsigned short h) {
  unsigned int u = ((unsigned int)h) << 16;
  return __uint_as_float(u);
}

__device__ __forceinline__ void gload16(const void* g, void* l) {
  __builtin_amdgcn_global_load_lds(
      (const __attribute__((address_space(1))) void*)g,
      (__attribute__((address_space(3))) void*)l, 16, 0, 0);
}

// ---------------- tiled transpose: out[M][K] = in[K][M], K,M multiples of 64 ----------------
__global__ __launch_bounds__(256) void transpose_f32(const float* __restrict__ in,
                                                     float* __restrict__ out,
                                                     int K, int M) {
  __shared__ float t[64][65];
  int tiles_m = M >> 6;
  int tk = blockIdx.x / tiles_m, tm = blockIdx.x % tiles_m;
  int k0 = tk * 64, m0 = tm * 64;
  int ty = threadIdx.x >> 4, tx = threadIdx.x & 15;
#pragma unroll
  for (int i = 0; i < 4; ++i) {
    f32x4 v = *(const f32x4*)(in + (size_t)(k0 + ty + 16 * i) * M + m0 + tx * 4);
    t[ty + 16 * i][tx * 4 + 0] = v[0];
    t[ty + 16 * i][tx * 4 + 1] = v[1];
    t[ty + 16 * i][tx * 4 + 2] = v[2];
    t[ty + 16 * i][tx * 4 + 3] = v[3];
  }
  __syncthreads();
#pragma unroll
  for (int i = 0; i < 4; ++i) {
    int m = ty + 16 * i;
    f32x4 v = {t[tx * 4 + 0][m], t[tx * 4 + 1][m], t[tx * 4 + 2][m], t[tx * 4 + 3][m]};
    *(f32x4*)(out + (size_t)(m0 + m) * K + k0 + tx * 4) = v;
  }
}

// ---------------- small GEMM: C[M,N] = AT[M,K] * BT[N,K]^T ----------------
// EPI 3: bf16 out = acc + bias[row]             (gemm3: h1, no dinv yet)
// EPI 1: bf16 out = (acc + bias[row])*dinv[col] (gemm6)
template <bool BF32, int EPI>
__device__ __forceinline__ void gemm_small(int bx, unsigned short* ldsb,
                                           const float* __restrict__ AT,
                                           const void* __restrict__ BTp,
                                           void* __restrict__ outp,
                                           const float* __restrict__ bias,
                                           const float* __restrict__ dinv,
                                           int M, int N, int K) {
  const int tid = threadIdx.x;
  const int m0 = (bx & (M / BM - 1)) * BM;
  const int n0 = (bx / (M / BM)) * BN;
  const int sr = tid >> 3;
  const int sc = (tid & 7) * 8;
  const float* Bf = (const float*)BTp;
  const unsigned short* Bh = (const unsigned short*)BTp;

  f32x4 a_f[2];
  f32x4 b_f[8][2];
  s16x8 b_h[8];

  auto stage_load = [&](int k0) {
    const float* pa = AT + (size_t)(m0 + sr) * K + k0 + sc;
    a_f[0] = *(const f32x4*)(pa);
    a_f[1] = *(const f32x4*)(pa + 4);
#pragma unroll
    for (int it = 0; it < 8; ++it) {
      int n = n0 + it * 32 + sr;
      if (BF32) {
        const float* p = Bf + (size_t)n * K + k0 + sc;
        b_f[it][0] = *(const f32x4*)(p);
        b_f[it][1] = *(const f32x4*)(p + 4);
      } else {
        b_h[it] = *(const s16x8*)(Bh + (size_t)n * K + k0 + sc);
      }
    }
  };

  auto stage_write = [&](int buf) {
    unsigned short* L = ldsb + buf * LDS_TILE;
    {
      s16x8 v;
#pragma unroll
      for (int j = 0; j < 8; ++j) v[j] = (short)f2bf(j < 4 ? a_f[0][j] : a_f[1][j - 4]);
      int idx = (sr * BK + sc) ^ ((sr & 7) << 3);
      *(s16x8*)(L + idx) = v;
    }
#pragma unroll
    for (int it = 0; it < 8; ++it) {
      int r = it * 32 + sr;
      s16x8 w;
      if (BF32) {
#pragma unroll
        for (int j = 0; j < 8; ++j)
          w[j] = (short)f2bf(j < 4 ? b_f[it][0][j] : b_f[it][1][j - 4]);
      } else {
        w = b_h[it];
      }
      int idx = BM * BK + ((r * BK + sc) ^ ((r & 7) << 3));
      *(s16x8*)(L + idx) = w;
    }
  };

  const int lane = tid & 63;
  const int wv = tid >> 6;
  const int g = lane >> 4, lr = lane & 15;

  int aidx[2][2], bidx[4][2];
#pragma unroll
  for (int m = 0; m < 2; ++m)
#pragma unroll
    for (int ks = 0; ks < 2; ++ks) {
      int r = m * 16 + lr;
      aidx[m][ks] = (r * BK + ks * 32 + g * 8) ^ ((r & 7) << 3);
    }
#pragma unroll
  for (int n = 0; n < 4; ++n)
#pragma unroll
    for (int ks = 0; ks < 2; ++ks) {
      int r = wv * 64 + n * 16 + lr;
      bidx[n][ks] = BM * BK + ((r * BK + ks * 32 + g * 8) ^ ((r & 7) << 3));
    }

  f32x4 acc[2][4];
#pragma unroll
  for (int m = 0; m < 2; ++m)
#pragma unroll
    for (int n = 0; n < 4; ++n) {
      f32x4 z = {0.f, 0.f, 0.f, 0.f};
      acc[m][n] = z;
    }

  auto compute = [&](int buf) {
    const unsigned short* L = ldsb + buf * LDS_TILE;
    s16x8 af[2][2], bfr[4][2];
#pragma unroll
    for (int m = 0; m < 2; ++m)
#pragma unroll
      for (int ks = 0; ks < 2; ++ks) af[m][ks] = *(const s16x8*)(L + aidx[m][ks]);
#pragma unroll
    for (int n = 0; n < 4; ++n)
#pragma unroll
      for (int ks = 0; ks < 2; ++ks) bfr[n][ks] = *(const s16x8*)(L + bidx[n][ks]);
#pragma unroll
    for (int m = 0; m < 2; ++m)
#pragma unroll
      for (int n = 0; n < 4; ++n)
#pragma unroll
        for (int ks = 0; ks < 2; ++ks)
          acc[m][n] = __builtin_amdgcn_mfma_f32_16x16x32_bf16(af[m][ks], bfr[n][ks],
                                                              acc[m][n], 0, 0, 0);
  };

  stage_load(0);
  stage_write(0);
  __syncthreads();
  int cur = 0;
  const int nt = K / BK;
  for (int t = 0; t < nt; ++t) {
    if (t + 1 < nt) stage_load((t + 1) * BK);
    compute(cur);
    if (t + 1 < nt) {
      stage_write(cur ^ 1);
      __syncthreads();
      cur ^= 1;
    }
  }

#pragma unroll
  for (int m = 0; m < 2; ++m)
#pragma unroll
    for (int n = 0; n < 4; ++n) {
      int col = n0 + wv * 64 + n * 16 + lr;
#pragma unroll
      for (int r = 0; r < 4; ++r) {
        int row = m0 + m * 16 + g * 4 + r;
        float v = acc[m][n][r];
        if constexpr (EPI == 3) {
          ((unsigned short*)outp)[(size_t)row * N + col] = f2bf(v + bias[row]);
        } else {
          ((unsigned short*)outp)[(size_t)row * N + col] = f2bf((v + bias[row]) * dinv[col]);
        }
      }
    }
}

// ---------------- prep: gemm3 blocks [0,256) + adj conv/rowsum blocks [256,4352) ----------------
__global__ __launch_bounds__(256) void prep(const float* __restrict__ adj,
                                            const float* __restrict__ x,
                                            const float* __restrict__ W1T,
                                            const float* __restrict__ b1,
                                            unsigned short* __restrict__ adjh,
                                            float* __restrict__ dinv,
                                            unsigned short* __restrict__ h1) {
  __shared__ unsigned short lds[2 * LDS_TILE];
  int bx = blockIdx.x;
  if (bx < 256) {
    gemm_small<true, 3>(bx, lds, W1T, x, h1, b1, nullptr, 256, 8192, 512);
    return;
  }
  bx -= 256;
  float* smf = (float*)lds;
  const int tid = threadIdx.x;
  float psum[2];
#pragma unroll
  for (int rr = 0; rr < 2; ++rr) {
    int row = bx * 2 + rr;
    const float* src = adj + (size_t)row * 8192;
    unsigned short* dst = adjh + (size_t)row * 8192;
    float s = 0.f;
    for (int c = tid * 8; c < 8192; c += 2048) {
      f32x4 v0 = __builtin_nontemporal_load((const f32x4*)(src + c));
      f32x4 v1 = __builtin_nontemporal_load((const f32x4*)(src + c + 4));
      s += v0[0] + v0[1] + v0[2] + v0[3] + v1[0] + v1[1] + v1[2] + v1[3];
      if (row >= c && row < c + 8) {  // add identity AFTER summing (deg = rowsum(adj)+1)
        int d = row - c;
        if (d < 4) v0[d] += 1.f; else v1[d - 4] += 1.f;
      }
      s16x8 o;
#pragma unroll
      for (int j = 0; j < 4; ++j) {
        o[j] = (short)f2bf(v0[j]);
        o[j + 4] = (short)f2bf(v1[j]);
      }
      *(s16x8*)(dst + c) = o;
    }
    psum[rr] = s;
  }
#pragma unroll
  for (int rr = 0; rr < 2; ++rr) {
    float s = psum[rr];
#pragma unroll
    for (int off = 32; off > 0; off >>= 1) s += __shfl_down(s, off, 64);
    if ((tid & 63) == 0) smf[rr * 4 + (tid >> 6)] = s;
  }
  __syncthreads();
  if (tid < 2) {
    float tot = smf[tid * 4] + smf[tid * 4 + 1] + smf[tid * 4 + 2] + smf[tid * 4 + 3];
    dinv[bx * 2 + tid] = rsqrtf(tot + 1.0f);
  }
}

// ---------------- hs1T = bf16(h1 * dinv[node]) ----------------
__global__ __launch_bounds__(256) void scale_hs(const unsigned short* __restrict__ h1,
                                                const float* __restrict__ dinv,
                                                unsigned short* __restrict__ hs1T) {
  size_t i = ((size_t)blockIdx.x * 256 + threadIdx.x) * 8;
  s16x8 v = *(const s16x8*)(h1 + i);
  int k = (int)(i & 8191);
  f32x4 d0 = *(const f32x4*)(dinv + k);
  f32x4 d1 = *(const f32x4*)(dinv + k + 4);
  s16x8 o;
#pragma unroll
  for (int j = 0; j < 4; ++j) {
    o[j] = (short)f2bf(bf2f((unsigned short)v[j]) * d0[j]);
    o[j + 4] = (short)f2bf(bf2f((unsigned short)v[j + 4]) * d1[j]);
  }
  *(s16x8*)(hs1T + i) = o;
}

// ---------------- big GEMM (split-K=4): P[z][8192][256] = adjh @ BT^T partials ----------------
// 256 blocks: blockIdx.x = z*64 + mt. 512 threads, 8 waves (2 M x 4 N), 64x64 per wave.
__global__ __launch_bounds__(512) void gemm_big(const unsigned short* __restrict__ A,
                                                const unsigned short* __restrict__ BT,
                                                float* __restrict__ P) {
  __shared__ unsigned short lds[NBUF * LDS_TILE2];  // 144 KB
  const int tid = threadIdx.x;
  const int mt = blockIdx.x & 63;
  const int z = blockIdx.x >> 6;
  const int m0 = mt * BM2;

  const int w = tid >> 6, l = tid & 63;
  const int lrow = l >> 3;
  const int swz = ((l & 7) * 16) ^ (lrow << 4);  // pre-swizzled byte-in-row (matches read XOR)

  const char* Asrc[2];
#pragma unroll
  for (int j = 0; j < 2; ++j) {
    int ra = w * 16 + j * 8 + lrow;
    Asrc[j] = (const char*)(A + (size_t)(m0 + ra) * KFULL + (size_t)z * KQ) + swz;
  }
  const char* Bsrc[4];
#pragma unroll
  for (int j = 0; j < 4; ++j) {
    int rb = j * 64 + w * 8 + lrow;
    Bsrc[j] = (const char*)(BT + (size_t)rb * KFULL + (size_t)z * KQ) + swz;
  }

  auto stage = [&](int buf, int k0) {  // 6 global_load_lds per thread
    unsigned short* L = lds + buf * LDS_TILE2;
#pragma unroll
    for (int j = 0; j < 2; ++j)
      gload16(Asrc[j] + (size_t)k0 * 2, L + (w * 16 + j * 8) * 64);
#pragma unroll
    for (int j = 0; j < 4; ++j)
      gload16(Bsrc[j] + (size_t)k0 * 2, L + 8192 + j * 4096 + w * 512);
  };

  const int wr = w >> 2, wc = w & 3;
  const int g = l >> 4, lr = l & 15;
  int aidx[4][2], bidx[4][2];
#pragma unroll
  for (int m = 0; m < 4; ++m)
#pragma unroll
    for (int ks = 0; ks < 2; ++ks) {
      int r = wr * 64 + m * 16 + lr;
      aidx[m][ks] = r * 64 + ((ks * 32 + g * 8) ^ ((r & 7) << 3));
    }
#pragma unroll
  for (int n = 0; n < 4; ++n)
#pragma unroll
    for (int ks = 0; ks < 2; ++ks) {
      int r = wc * 64 + n * 16 + lr;
      bidx[n][ks] = 8192 + r * 64 + ((ks * 32 + g * 8) ^ ((r & 7) << 3));
    }

  f32x4 acc[4][4];
#pragma unroll
  for (int m = 0; m < 4; ++m)
#pragma unroll
    for (int n = 0; n < 4; ++n) {
      f32x4 zz = {0.f, 0.f, 0.f, 0.f};
      acc[m][n] = zz;
    }

  stage(0, 0);
  stage(1, BK2);
  stage(2, 2 * BK2);
  int cur = 0;
  const int nt = KQ / BK2;  // 32
  for (int t = 0; t < nt; ++t) {
    if (t + 2 < nt)      asm volatile("s_waitcnt vmcnt(12)" ::: "memory");
    else if (t + 1 < nt) asm volatile("s_waitcnt vmcnt(6)" ::: "memory");
    else                 asm volatile("s_waitcnt vmcnt(0)" ::: "memory");
    __builtin_amdgcn_sched_barrier(0);
    asm volatile("s_barrier" ::: "memory");
    __builtin_amdgcn_sched_barrier(0);

    const unsigned short* L = lds + cur * LDS_TILE2;
    s16x8 af[4][2], bfr[4][2];
#pragma unroll
    for (int m = 0; m < 4; ++m)
#pragma unroll
      for (int ks = 0; ks < 2; ++ks) af[m][ks] = *(const s16x8*)(L + aidx[m][ks]);
#pragma unroll
    for (int n = 0; n < 4; ++n)
#pragma unroll
      for (int ks = 0; ks < 2; ++ks) bfr[n][ks] = *(const s16x8*)(L + bidx[n][ks]);
    __builtin_amdgcn_s_setprio(1);
#pragma unroll
    for (int m = 0; m < 4; ++m)
#pragma unroll
      for (int n = 0; n < 4; ++n)
#pragma unroll
        for (int ks = 0; ks < 2; ++ks)
          acc[m][n] = __builtin_amdgcn_mfma_f32_16x16x32_bf16(af[m][ks], bfr[n][ks],
                                                              acc[m][n], 0, 0, 0);
    __builtin_amdgcn_s_setprio(0);

    __builtin_amdgcn_sched_barrier(0);
    asm volatile("s_barrier" ::: "memory");  // all waves done reading buf[cur]
    __builtin_amdgcn_sched_barrier(0);
    if (t + 3 < nt) stage(cur, (t + 3) * BK2);
    cur = (cur == NBUF - 1) ? 0 : cur + 1;
  }

  float* Pz = P + (size_t)z * 8192 * 256;
#pragma unroll
  for (int m = 0; m < 4; ++m)
#pragma unroll
    for (int n = 0; n < 4; ++n) {
      int col = wc * 64 + n * 16 + lr;
#pragma unroll
      for (int r = 0; r < 4; ++r) {
        int row = m0 + wr * 64 + m * 16 + g * 4 + r;
        Pz[(size_t)row * 256 + col] = acc[m][n][r];
      }
    }
}

// ---------------- reduce1: hln = LN(GELU((ΣPz)*dinv[row])), bf16 out ----------------
__global__ __launch_bounds__(256) void reduce_ln(const float* __restrict__ P,
                                                 const float* __restrict__ dinv,
                                                 const float* __restrict__ gamma,
                                                 const float* __restrict__ beta,
                                                 unsigned short* __restrict__ hln) {
  const size_t ZSTR = (size_t)8192 * 256;
  int row = blockIdx.x * 4 + (threadIdx.x >> 6);
  int l = threadIdx.x & 63;
  const float* p = P + (size_t)row * 256 + l * 4;
  f32x4 a = *(const f32x4*)p;
  f32x4 b = *(const f32x4*)(p + ZSTR);
  f32x4 c = *(const f32x4*)(p + 2 * ZSTR);
  f32x4 d = *(const f32x4*)(p + 3 * ZSTR);
  float di = dinv[row];
  float gl[4];
  float s = 0.f, q = 0.f;
#pragma unroll
  for (int j = 0; j < 4; ++j) {
    float v = (a[j] + b[j] + c[j] + d[j]) * di;
    float gv = 0.5f * v * (1.0f + erff(v * 0.70710678118654752440f));
    gl[j] = gv;
    s += gv;
    q += gv * gv;
  }
#pragma unroll
  for (int off = 1; off < 64; off <<= 1) {
    s += __shfl_xor(s, off, 64);
    q += __shfl_xor(q, off, 64);
  }
  float mu = s * (1.0f / 256.0f);
  float var = q * (1.0f / 256.0f) - mu * mu;
  float rs = rsqrtf(fmaxf(var, 0.f) + 1e-6f);
  f32x4 gm = *(const f32x4*)(gamma + l * 4);
  f32x4 bt = *(const f32x4*)(beta + l * 4);
  unsigned short o4[4];
#pragma unroll
  for (int j = 0; j < 4; ++j)
    o4[j] = f2bf((gl[j] - mu) * rs * gm[j] + bt[j]);
  *(unsigned long long*)(hln + (size_t)row * 256 + l * 4) =
      *(const unsigned long long*)o4;
}

// ---------------- reduce2: out fp32 = (ΣPz)*dinv[row] ----------------
__global__ __launch_bounds__(256) void reduce_sc(const float* __restrict__ P,
                                                 const float* __restrict__ dinv,
                                                 float* __restrict__ out) {
  const size_t ZSTR = (size_t)8192 * 256;
  size_t i = ((size_t)blockIdx.x * 256 + threadIdx.x) * 4;
  int row = (int)(i >> 8);
  f32x4 a = *(const f32x4*)(P + i);
  f32x4 b = *(const f32x4*)(P + ZSTR + i);
  f32x4 c = *(const f32x4*)(P + 2 * ZSTR + i);
  f32x4 d = *(const f32x4*)(P + 3 * ZSTR + i);
  float di = dinv[row];
  f32x4 o;
#pragma unroll
  for (int j = 0; j < 4; ++j) o[j] = (a[j] + b[j] + c[j] + d[j]) * di;
  *(f32x4*)(out + i) = o;
}

// ---------------- GEMM6: hs2T = bf16((hln @ W2 + b2)^T * dinv[col]) ----------------
__global__ __launch_bounds__(256) void gemm6_k(const float* __restrict__ W2T,
                                               const unsigned short* __restrict__ hln,
                                               unsigned short* __restrict__ hs2T,
                                               const float* __restrict__ b2,
                                               const float* __restrict__ dinv) {
  __shared__ unsigned short lds[2 * LDS_TILE];
  gemm_small<false, 1>(blockIdx.x, lds, W2T, hln, hs2T, b2, dinv, 256, 8192, 256);
}

// ---------------- launch ----------------
extern "C" void kernel_launch(void* const* d_in, const int* in_sizes, int n_in,
                              void* d_out, int out_size, void* d_ws, size_t ws_size,
                              hipStream_t stream) {
  (void)in_sizes; (void)n_in; (void)out_size; (void)ws_size;
  const float* x     = (const float*)d_in[0];
  const float* adj   = (const float*)d_in[1];
  const float* W1    = (const float*)d_in[2];
  const float* b1    = (const float*)d_in[3];
  const float* W2    = (const float*)d_in[4];
  const float* b2    = (const float*)d_in[5];
  const float* gamma = (const float*)d_in[6];
  const float* beta  = (const float*)d_in[7];
  float* out = (float*)d_out;

  char* ws = (char*)d_ws;
  float* dinv          = (float*)ws;                           // 32 KB
  float* W1T           = (float*)(ws + (64 << 10));            // 512 KB [256][512]
  float* W2T           = (float*)(ws + (640 << 10));           // 256 KB [256][256]
  unsigned short* h1   = (unsigned short*)(ws + (1 << 20));    // 4 MB [256][8192] (pre-dinv)
  unsigned short* hs1T = (unsigned short*)(ws + (8 << 20));    // 4 MB [256][8192]
  unsigned short* hln  = (unsigned short*)(ws + (16 << 20));   // 4 MB [8192][256]
  unsigned short* hs2T = (unsigned short*)(ws + (24 << 20));   // 4 MB [256][8192]
  float* P             = (float*)(ws + (32 << 20));            // 32 MB [4][8192][256]
  unsigned short* adjh = (unsigned short*)(ws + (64 << 20));   // 128 MB [8192][8192] (adj+I)

  // 0) weight transposes -> [M][K] fp32
  transpose_f32<<<32, 256, 0, stream>>>(W1, W1T, 512, 256);
  transpose_f32<<<16, 256, 0, stream>>>(W2, W2T, 256, 256);
  // 1) gemm3 (h1 bf16, no dinv) + adj->bf16(+I) + rowsum->dinv, fused
  prep<<<4352, 256, 0, stream>>>(adj, x, W1T, b1, adjh, dinv, h1);
  // 2) hs1T = bf16(h1 * dinv[node])
  scale_hs<<<1024, 256, 0, stream>>>(h1, dinv, hs1T);
  // 3) P = split-K=4 partials of (adj+I) @ hs1
  gemm_big<<<256, 512, 0, stream>>>(adjh, hs1T, P);
  // 4) hln = LN(GELU((ΣPz)*dinv[row]))
  reduce_ln<<<2048, 256, 0, stream>>>(P, dinv, gamma, beta, hln);
  // 5) hs2T = bf16((hln @ W2 + b2)^T * dinv[node])
  gemm6_k<<<256, 256, 0, stream>>>(W2T, hln, hs2T, b2, dinv);
  // 6) P = split-K=4 partials of (adj+I) @ hs2
  gemm_big<<<256, 512, 0, stream>>>(adjh, hs2T, P);
  // 7) out = (ΣPz)*dinv[row]
  reduce_sc<<<2048, 256, 0, stream>>>(P, dinv, out);
}